// Round 1
// baseline (285.921 us; speedup 1.0000x reference)
//
#include <hip/hip_runtime.h>

typedef unsigned long long u64;

#define NTOK 131072
#define DIMS 1024
#define NT   256
#define TPB  64   // tokens per block in dist kernel

// ---------------------------------------------------------------------------
// Kernel A: build ternary signatures as 2-plane bitmasks.
// Tile t, plane p (0=pos,1=neg), word w = c*4+j (c in 0..3, j in 0..3):
//   bit L of word = plane-pred of sig[t][c*256 + L*4 + j]
// This matches the ballot order used by the dist kernel's float4 loads.
// sig[t] = 32 u64 (16 pos words then 16 neg words), pops[t] = nnz(sig row).
// ---------------------------------------------------------------------------
__global__ void sig_kernel(const float* __restrict__ base,
                           const float* __restrict__ deltas,
                           u64* __restrict__ sig,
                           int* __restrict__ pops)
{
    const int t    = blockIdx.x;    // tile 0..255
    const int lane = threadIdx.x;   // 0..63
    int pop = 0;
    #pragma unroll
    for (int c = 0; c < 4; ++c) {
        #pragma unroll
        for (int j = 0; j < 4; ++j) {
            const int d = c * 256 + lane * 4 + j;
            const float b  = base[d];
            const float dl = (t > 0) ? deltas[(size_t)(t - 1) * DIMS + d] : 0.0f;
            const bool use_d = (dl != 0.0f);
            const bool pos = use_d ? (dl > 0.0f) : (b > 0.0f);
            const bool neg = use_d ? (dl < 0.0f) : (b < 0.0f);
            const u64 bp = __ballot(pos);
            const u64 bn = __ballot(neg);
            if (lane == 0) {
                sig[(size_t)t * 32 + (c * 4 + j)]      = bp;
                sig[(size_t)t * 32 + 16 + (c * 4 + j)] = bn;
            }
            pop += __popcll(bp) + __popcll(bn);
        }
    }
    if (lane == 0) pops[t] = pop;
}

// ---------------------------------------------------------------------------
// Kernel B: per block, 64 tokens x all 256 tiles.
// Wave w (0..3): lane L owns tile w*64+L, signature kept in 64 VGPRs.
// Phase 1: each wave ballots 16 token rows into LDS bitmasks (coalesced
//          float4 loads of x). Phase 2: every wave scans all 64 tokens,
//          AND+popcount against its in-register signature, writes the
//          distance row slice, and min-reduces (dist<<8)|tile for argmin.
// ---------------------------------------------------------------------------
__global__ __launch_bounds__(256)
void dist_kernel(const float* __restrict__ x,
                 const u64* __restrict__ sig,
                 const int* __restrict__ pops,
                 float* __restrict__ idx_out,
                 float* __restrict__ dist_out)
{
    __shared__ u64 lmask[TPB][32];   // 16 KB: [token][word], words 0..15 pos, 16..31 neg
    __shared__ int lpopx[TPB];
    __shared__ int lkey[TPB][4];

    const int lane = threadIdx.x & 63;
    const int w    = threadIdx.x >> 6;
    const int tile = w * 64 + lane;
    const int tok0 = blockIdx.x * TPB;

    // load this lane's tile signature into registers (one-time, L2/L3-cached)
    u64 sp[16], sn[16];
    {
        const u64* sgp = sig + (size_t)tile * 32;
        #pragma unroll
        for (int i = 0; i < 16; ++i) sp[i] = sgp[i];
        #pragma unroll
        for (int i = 0; i < 16; ++i) sn[i] = sgp[16 + i];
    }
    const int pop_s = pops[tile];

    // ---- phase 1: build token bitmasks in LDS ----
    for (int tk = 0; tk < 16; ++tk) {
        const int tok = w * 16 + tk;
        const float4* xr = (const float4*)(x + (size_t)(tok0 + tok) * DIMS);
        int pop = 0;
        #pragma unroll
        for (int c = 0; c < 4; ++c) {
            const float4 v = xr[c * 64 + lane];
            const u64 bp0 = __ballot(v.x > 0.0f); const u64 bn0 = __ballot(v.x < 0.0f);
            const u64 bp1 = __ballot(v.y > 0.0f); const u64 bn1 = __ballot(v.y < 0.0f);
            const u64 bp2 = __ballot(v.z > 0.0f); const u64 bn2 = __ballot(v.z < 0.0f);
            const u64 bp3 = __ballot(v.w > 0.0f); const u64 bn3 = __ballot(v.w < 0.0f);
            if (lane == 0) {
                lmask[tok][c * 4 + 0] = bp0;  lmask[tok][16 + c * 4 + 0] = bn0;
                lmask[tok][c * 4 + 1] = bp1;  lmask[tok][16 + c * 4 + 1] = bn1;
                lmask[tok][c * 4 + 2] = bp2;  lmask[tok][16 + c * 4 + 2] = bn2;
                lmask[tok][c * 4 + 3] = bp3;  lmask[tok][16 + c * 4 + 3] = bn3;
            }
            pop += __popcll(bp0) + __popcll(bn0) + __popcll(bp1) + __popcll(bn1)
                 + __popcll(bp2) + __popcll(bn2) + __popcll(bp3) + __popcll(bn3);
        }
        if (lane == 0) lpopx[tok] = pop;
    }
    __syncthreads();

    // ---- phase 2: distances + argmin ----
    for (int tok = 0; tok < TPB; ++tok) {
        int c0 = 0, c1 = 0, c2 = 0, c3 = 0;   // 4 accumulators to break bcnt chain
        #pragma unroll
        for (int i = 0; i < 16; i += 4) {
            c0 += __popcll(lmask[tok][i + 0] & sp[i + 0]);
            c1 += __popcll(lmask[tok][i + 1] & sp[i + 1]);
            c2 += __popcll(lmask[tok][i + 2] & sp[i + 2]);
            c3 += __popcll(lmask[tok][i + 3] & sp[i + 3]);
            c0 += __popcll(lmask[tok][16 + i + 0] & sn[i + 0]);
            c1 += __popcll(lmask[tok][16 + i + 1] & sn[i + 1]);
            c2 += __popcll(lmask[tok][16 + i + 2] & sn[i + 2]);
            c3 += __popcll(lmask[tok][16 + i + 3] & sn[i + 3]);
        }
        const int cross = (c0 + c1) + (c2 + c3);
        const int dist  = lpopx[tok] + pop_s - 2 * cross;
        dist_out[(size_t)(tok0 + tok) * NT + tile] = (float)dist;

        int key = (dist << 8) | tile;          // argmin with first-index tiebreak
        #pragma unroll
        for (int off = 32; off >= 1; off >>= 1)
            key = min(key, __shfl_xor(key, off));
        if (lane == 0) lkey[tok][w] = key;
    }
    __syncthreads();

    if (threadIdx.x < TPB) {
        const int tok = threadIdx.x;
        const int k = min(min(lkey[tok][0], lkey[tok][1]),
                          min(lkey[tok][2], lkey[tok][3]));
        idx_out[tok0 + tok] = (float)(k & 255);
    }
}

extern "C" void kernel_launch(void* const* d_in, const int* in_sizes, int n_in,
                              void* d_out, int out_size, void* d_ws, size_t ws_size,
                              hipStream_t stream)
{
    const float* x      = (const float*)d_in[0];
    const float* base   = (const float*)d_in[1];
    const float* deltas = (const float*)d_in[2];

    u64* sig  = (u64*)d_ws;                          // 256*32*8 = 65536 B
    int* pops = (int*)((char*)d_ws + 65536);         // 256*4 B

    float* idx_out  = (float*)d_out;                 // N floats (tile indices)
    float* dist_out = idx_out + NTOK;                // N*T floats

    sig_kernel<<<NT, 64, 0, stream>>>(base, deltas, sig, pops);
    dist_kernel<<<NTOK / TPB, 256, 0, stream>>>(x, sig, pops, idx_out, dist_out);
}